// Round 19
// baseline (206.418 us; speedup 1.0000x reference)
//
#include <hip/hip_runtime.h>

#define BB 8
#define TT 128
#define EE 256
#define VV 8192
#define LL 5
#define NROWS (BB*TT)   // 1024

typedef __attribute__((ext_vector_type(8))) short bf16x8;
typedef __attribute__((ext_vector_type(4))) float f32x4;

__device__ inline ushort f2bf(float f) {
    union { float f; unsigned u; } c; c.f = f;
    unsigned u = c.u;
    return (ushort)((u + 0x7FFF + ((u >> 16) & 1)) >> 16);  // RNE
}
__device__ inline float bf2f(ushort u) {
    union { unsigned u; float f; } c; c.u = ((unsigned)u) << 16;
    return c.f;
}

// async global->LDS copy, 16B per lane; lds base wave-uniform (HW adds lane*16)
__device__ __forceinline__ void gload_lds16(const void* g, void* l) {
    __builtin_amdgcn_global_load_lds((const __attribute__((address_space(1))) unsigned int*)g,
                                     (__attribute__((address_space(3))) unsigned int*)l,
                                     16, 0, 0);
}

// SW128 weight layout: W^T row r (output col), k in [0,256):
//   ushort index = r*256 + (k & 128) + ((k & 127) ^ ((r & 7) << 3))
// Full-width bf16 tile layout (Ybuf): row*256 + (k & 128) + ((k & 127) ^ ((row & 7) << 3))

// ---------------- layer0 kernel: blocks<256 = layer-0 qkv+attn (raw weights, inline emb);
// blocks>=256 = prep jobs (loss zero / WlmT / WTs transposes) riding along.
__global__ __launch_bounds__(512, 2) void layer0_kernel(
        const int* __restrict__ idxs, const float* __restrict__ emb, const float* __restrict__ pos,
        const float* __restrict__ Wq, const float* __restrict__ Wk,
        const float* __restrict__ Wv, const float* __restrict__ Wfc,
        const float* __restrict__ Wlm,
        float* __restrict__ y_out, ushort* __restrict__ WTs, ushort* __restrict__ WlmT,
        float* __restrict__ loss_cell) {
    __shared__ __align__(16) ushort Xs[128*128];   // 32KB (transpose blocks alias as ts)
    __shared__ __align__(16) ushort Bs[32*128];    // 8KB
    __shared__ __align__(16) float QS[8*132], KS[8*132], VS[8*132], MS[8*132]; // 16.9KB
    int tid = threadIdx.x, lane = tid & 63, w = tid >> 6;   // 8 waves
    int blk = blockIdx.x;

    if (blk >= 256) {
        int id = blk - 256;
        if (id == 0) {
            if (tid == 0) *loss_cell = 0.f;
            return;
        }
        ushort (*ts)[72] = (ushort(*)[72])Xs;
        if (id < 513) {
            int idw = id - 1;
            int v0 = (idw & 127) * 64, k0 = (idw >> 7) * 64;
            for (int kk = w; kk < 64; kk += 8)
                ts[lane][kk] = f2bf(Wlm[(size_t)(k0 + kk)*VV + v0 + lane]);
            __syncthreads();
            for (int vv = w; vv < 64; vv += 8) {
                int r = v0 + vv, k = k0 + lane;
                WlmT[(size_t)r*256 + (k & 128) + ((k & 127) ^ ((r & 7) << 3))] = ts[vv][lane];
            }
            return;
        }
        {
            int idm = id - 513;
            int mat = idm >> 4, tile = idm & 15;
            int l = mat >> 2, type = mat & 3;
            const float* src = (type == 0 ? Wq : type == 1 ? Wk : type == 2 ? Wv : Wfc) + l*EE*EE;
            ushort* dst = WTs + mat*EE*EE;
            int i0 = (tile >> 2) * 64, o0 = (tile & 3) * 64;
            for (int ii = w; ii < 64; ii += 8)
                ts[lane][ii] = f2bf(src[(i0 + ii)*EE + o0 + lane]);
            __syncthreads();
            for (int oo = w; oo < 64; oo += 8) {
                int r = o0 + oo, k = i0 + lane;
                dst[(size_t)r*256 + (k & 128) + ((k & 127) ^ ((r & 7) << 3))] = ts[oo][lane];
            }
            return;
        }
    }

    // ---- layer-0 qkv+attn ----
    int b  = blk >> 5;
    int h0 = (blk & 31) * 8;

    f32x4 acc[2] = {};
    int rband = w*16 + (lane & 15);
    int kq = (lane >> 4) * 8;

    #pragma unroll
    for (int half = 0; half < 2; ++half) {
        if (half) __syncthreads();
        {
            int rsub = lane >> 5, cb = (lane & 31) * 4;
            for (int rr2 = w*2; rr2 < 128; rr2 += 16) {
                int rr = rr2 + rsub;
                int id = idxs[b*TT + rr];
                float4 v = *(const float4*)&emb[(size_t)id*EE + half*128 + cb];
                float4 p = *(const float4*)&pos[rr*EE + half*128 + cb];
                ushort4 hh;
                hh.x = f2bf(v.x + p.x); hh.y = f2bf(v.y + p.y);
                hh.z = f2bf(v.z + p.z); hh.w = f2bf(v.w + p.w);
                *(ushort4*)&Xs[rr*128 + (cb ^ ((rr & 7) << 3))] = hh;
            }
        }
        {
            int c = tid >> 4;            // 0..31
            int kb8 = (tid & 15) * 8;
            ushort tmp[8];
            if (c < 24) {
                int mat = c >> 3;
                int col = h0 + (c & 7);
                const float* Wm = mat == 0 ? Wq : (mat == 1 ? Wk : Wv);
                #pragma unroll
                for (int i = 0; i < 8; ++i)
                    tmp[i] = f2bf(Wm[(size_t)(half*128 + kb8 + i)*EE + col]);
            } else {
                #pragma unroll
                for (int i = 0; i < 8; ++i) tmp[i] = 0;
            }
            ushort* dst = &Bs[c*128 + (kb8 ^ ((c & 7) << 3))];
            *(ushort4*)dst       = *(ushort4*)&tmp[0];
            *(ushort4*)(dst + 4) = *(ushort4*)&tmp[4];
        }
        __syncthreads();
        for (int ks = 0; ks < 4; ++ks) {
            int kk = ks*32 + kq;
            bf16x8 a = *(const bf16x8*)&Xs[rband*128 + (kk ^ ((rband & 7) << 3))];
            #pragma unroll
            for (int ct = 0; ct < 2; ++ct) {
                int c = ct*16 + (lane & 15);
                bf16x8 bb = *(const bf16x8*)&Bs[c*128 + (kk ^ ((c & 7) << 3))];
                acc[ct] = __builtin_amdgcn_mfma_f32_16x16x32_bf16(a, bb, acc[ct], 0, 0, 0);
            }
        }
    }
    {
        int r_ = w*16 + ((lane >> 4) << 2);
        #pragma unroll
        for (int ct = 0; ct < 2; ++ct) {
            int col24 = ct*16 + (lane & 15);
            #pragma unroll
            for (int j = 0; j < 4; ++j) {
                float val = acc[ct][j];
                int row = r_ + j;
                if (col24 < 8)       QS[col24*132 + row] = val;
                else if (col24 < 16) KS[(col24-8)*132 + row] = val;
                else if (col24 < 24) VS[(col24-16)*132 + row] = val;
            }
        }
    }
    __syncthreads();

    int g = w, lg = lane;
    {
        int j0 = lg*2;
        float k0 = KS[g*132 + j0], k1 = KS[g*132 + j0 + 1];
        float q0j = QS[g*132 + j0], q1j = QS[g*132 + j0 + 1];
        float pmax = fmaxf(q0j, q1j), pmin = fminf(q0j, q1j);
        #pragma unroll
        for (int d = 1; d < 64; d <<= 1) {
            float om = __shfl_down(pmax, d);
            float on = __shfl_down(pmin, d);
            if (lg + d < 64) { pmax = fmaxf(pmax, om); pmin = fminf(pmin, on); }
        }
        float nx = __shfl_down(pmax, 1), nn = __shfl_down(pmin, 1);
        float sp1 = (lg == 63) ? q1j : fmaxf(q1j, nx);
        float sn1 = (lg == 63) ? q1j : fminf(q1j, nn);
        MS[g*132 + j0]     = (k0 >= 0.f) ? k0*pmax : k0*pmin;
        MS[g*132 + j0 + 1] = (k1 >= 0.f) ? k1*sp1  : k1*sn1;
    }
    __syncthreads();

    {
        float outp[32];
        #pragma unroll
        for (int r = 0; r < 32; ++r) outp[r] = 0.f;
        int c = lg & 15, rg = lg >> 4;
        int rbase = rg * 32;
        for (int jt = 0; jt < 8; ++jt) {
            int j = jt*16 + c;
            float kj = KS[g*132 + j];
            float mj = MS[g*132 + j];
            float vj = VS[g*132 + j];
            float P[32];
            float z = 0.f;
            #pragma unroll
            for (int r = 0; r < 32; ++r) {
                int i = rbase + r;
                float e = __expf(QS[g*132 + i] * kj - mj);
                e = (i >= j) ? e : 0.f;
                P[r] = e;
                z += e;
            }
            z += __shfl_xor(z, 16);
            z += __shfl_xor(z, 32);
            float rv = vj / z;
            #pragma unroll
            for (int r = 0; r < 32; ++r) outp[r] += P[r] * rv;
        }
        #pragma unroll
        for (int r = 0; r < 32; ++r) {
            float v = outp[r];
            v += __shfl_xor(v, 1);
            v += __shfl_xor(v, 2);
            v += __shfl_xor(v, 4);
            v += __shfl_xor(v, 8);
            outp[r] = v;
        }
        __syncthreads();
        if (c == 0) {
            #pragma unroll
            for (int r = 0; r < 32; ++r)
                VS[g*132 + rbase + r] = outp[r];
        }
    }
    __syncthreads();

    {
        int row = tid >> 2, cp = (tid & 3) * 2;
        int id = idxs[b*TT + row];
        float2 ev = *(const float2*)&emb[(size_t)id*EE + h0 + cp];
        float2 pv = *(const float2*)&pos[row*EE + h0 + cp];
        float2 ov;
        ov.x = ev.x + pv.x + VS[cp*132 + row];
        ov.y = ev.y + pv.y + VS[(cp+1)*132 + row];
        *(float2*)&y_out[(size_t)(b*TT + row)*EE + h0 + cp] = ov;
    }
}

// ---------------- fused layer kernel v2 (l=1..4): 80KB LDS -> 2 blocks/CU.
// z = y + relu(y@Wfc_prev + b) IN-PLACE in Ybuf (wave-private rows), then qkv + attn.
__global__ __launch_bounds__(512, 4) void layer_kernel(
        const float* __restrict__ y_in, float* __restrict__ y_out,
        const ushort* __restrict__ WTfc, const float* __restrict__ bfc_prev,
        const ushort* __restrict__ WTqkv) {
    __shared__ __align__(16) ushort Ybuf[128*256];   // 64KB: y bf16, then z in-place
    __shared__ __align__(16) char U[16384];          // BsF[64][128] U Bsq[32][256] U QS/KS/VS
    ushort* BsF = (ushort*)U;                        // [64][128] (per fc stage)
    ushort* Bsq = (ushort*)U;                        // [32][256] (qkv, single stage)
    float* QS = (float*)U;                           // [8][132] after Bsq dead
    float* KS = QS + 8*132;
    float* VS = KS + 8*132;                          // total 12.7KB
    int tid = threadIdx.x, lane = tid & 63, w = tid >> 6;   // 8 waves
    int b  = blockIdx.x >> 5;
    int h0 = (blockIdx.x & 31) * 8;
    int rband = w*16 + (lane & 15);
    int kq = (lane >> 4) * 8;

    // ---- stage y (full width) ----
    for (int rr = w; rr < 128; rr += 8) {
        float4 v = *(const float4*)&y_in[(size_t)(b*TT + rr)*EE + lane*4];
        ushort4 hh;
        hh.x = f2bf(v.x); hh.y = f2bf(v.y); hh.z = f2bf(v.z); hh.w = f2bf(v.w);
        int k0 = lane*4;
        *(ushort4*)&Ybuf[rr*256 + (k0 & 128) + ((k0 & 127) ^ ((rr & 7) << 3))] = hh;
    }

    // ---- fc: 8 stages (2 halves x 4 col-groups of 64) ----
    f32x4 accz[4][4] = {};
    #pragma unroll
    for (int half = 0; half < 2; ++half) {
        #pragma unroll
        for (int cg = 0; cg < 4; ++cg) {
            __syncthreads();        // BsF free (prev stage's MFMA reads done in all waves)
            {
                int rg0 = w*8;
                const ushort* s0 = WTfc + (size_t)(cg*64 + rg0 + (lane >> 4))*256
                                 + half*128 + (lane & 15)*8;
                gload_lds16(s0, &BsF[(size_t)rg0*128]);
                const ushort* s1 = WTfc + (size_t)(cg*64 + rg0 + 4 + (lane >> 4))*256
                                 + half*128 + (lane & 15)*8;
                gload_lds16(s1, &BsF[(size_t)(rg0 + 4)*128]);
            }
            __syncthreads();
            for (int ks = 0; ks < 4; ++ks) {
                int kk = ks*32 + kq;
                bf16x8 a = *(const bf16x8*)&Ybuf[rband*256 + half*128 + (kk ^ ((rband & 7) << 3))];
                #pragma unroll
                for (int n = 0; n < 4; ++n) {
                    int c = n*16 + (lane & 15);
                    bf16x8 bb = *(const bf16x8*)&BsF[c*128 + (kk ^ ((c & 7) << 3))];
                    accz[cg][n] = __builtin_amdgcn_mfma_f32_16x16x32_bf16(a, bb, accz[cg][n], 0, 0, 0);
                }
            }
        }
    }
    // epilogue: z = y + relu(acc + bias) IN-PLACE (wave-private rows; no barrier needed)
    {
        int grow0 = w*16 + ((lane >> 4) << 2);
        #pragma unroll
        for (int cg = 0; cg < 4; ++cg) {
            #pragma unroll
            for (int n = 0; n < 4; ++n) {
                int col = cg*64 + n*16 + (lane & 15);
                float bias = bfc_prev[col];
                int coff = (col & 128), csub = col & 127;
                #pragma unroll
                for (int j = 0; j < 4; ++j) {
                    int row = grow0 + j;
                    int sw = coff + (csub ^ ((row & 7) << 3));
                    float y = bf2f(Ybuf[row*256 + sw]);
                    float z = y + fmaxf(accz[cg][n][j] + bias, 0.f);
                    Ybuf[row*256 + sw] = f2bf(z);
                }
            }
        }
    }

    // ---- qkv: single-stage B (32 rows x 256 k = 16KB) ----
    __syncthreads();   // all waves' BsF reads done before Bsq overwrite
    {
        int r0i = w*4 + (lane >> 5);
        int rv0 = r0i < 24 ? r0i : 23;
        const ushort* s0 = WTqkv + (size_t)(rv0 >> 3)*EE*EE + (size_t)(h0 + (rv0 & 7))*256
                         + (lane & 31)*8;
        gload_lds16(s0, &Bsq[(size_t)(w*4)*256]);
        int r1i = r0i + 2;
        int rv1 = r1i < 24 ? r1i : 23;
        const ushort* s1 = WTqkv + (size_t)(rv1 >> 3)*EE*EE + (size_t)(h0 + (rv1 & 7))*256
                         + (lane & 31)*8;
        gload_lds16(s1, &Bsq[(size_t)(w*4 + 2)*256]);
    }
    __syncthreads();
    f32x4 acc[2] = {};
    for (int ks = 0; ks < 8; ++ks) {
        int kk = ks*32 + kq;
        bf16x8 a = *(const bf16x8*)&Ybuf[rband*256 + (kk & 128) + ((kk & 127) ^ ((rband & 7) << 3))];
        #pragma unroll
        for (int ct = 0; ct < 2; ++ct) {
            int c = ct*16 + (lane & 15);
            bf16x8 bb = *(const bf16x8*)&Bsq[c*256 + (kk & 128) + ((kk & 127) ^ ((c & 7) << 3))];
            acc[ct] = __builtin_amdgcn_mfma_f32_16x16x32_bf16(a, bb, acc[ct], 0, 0, 0);
        }
    }
    __syncthreads();   // all waves' Bsq reads done before scatter overwrites U

    // scatter q|k|v
    {
        int r_ = w*16 + ((lane >> 4) << 2);
        #pragma unroll
        for (int ct = 0; ct < 2; ++ct) {
            int col24 = ct*16 + (lane & 15);
            #pragma unroll
            for (int j = 0; j < 4; ++j) {
                float val = acc[ct][j];
                int row = r_ + j;
                if (col24 < 8)       QS[col24*132 + row] = val;
                else if (col24 < 16) KS[(col24-8)*132 + row] = val;
                else if (col24 < 24) VS[(col24-16)*132 + row] = val;
            }
        }
    }
    __syncthreads();

    // ---- attention (exp-once); m kept in registers, delivered via shuffle ----
    int g = w, lg = lane;
    float m0, m1;
    {
        int j0 = lg*2;
        float k0 = KS[g*132 + j0], k1 = KS[g*132 + j0 + 1];
        float q0j = QS[g*132 + j0], q1j = QS[g*132 + j0 + 1];
        float pmax = fmaxf(q0j, q1j), pmin = fminf(q0j, q1j);
        #pragma unroll
        for (int d = 1; d < 64; d <<= 1) {
            float om = __shfl_down(pmax, d);
            float on = __shfl_down(pmin, d);
            if (lg + d < 64) { pmax = fmaxf(pmax, om); pmin = fminf(pmin, on); }
        }
        float nx = __shfl_down(pmax, 1), nn = __shfl_down(pmin, 1);
        float sp1 = (lg == 63) ? q1j : fmaxf(q1j, nx);
        float sn1 = (lg == 63) ? q1j : fminf(q1j, nn);
        m0 = (k0 >= 0.f) ? k0*pmax : k0*pmin;
        m1 = (k1 >= 0.f) ? k1*sp1  : k1*sn1;
    }
    {
        float outp[32];
        #pragma unroll
        for (int r = 0; r < 32; ++r) outp[r] = 0.f;
        int c = lg & 15, rg = lg >> 4;
        int rbase = rg * 32;
        for (int jt = 0; jt < 8; ++jt) {
            int j = jt*16 + c;
            int srcl = jt*8 + (c >> 1);
            float me = __shfl(m0, srcl);
            float mo = __shfl(m1, srcl);
            float mj = (c & 1) ? mo : me;
            float kj = KS[g*132 + j];
            float vj = VS[g*132 + j];
            float P[32];
            float z = 0.f;
            #pragma unroll
            for (int r = 0; r < 32; ++r) {
                int i = rbase + r;
                float e = __expf(QS[g*132 + i] * kj - mj);
                e = (i >= j) ? e : 0.f;
                P[r] = e;
                z += e;
            }
            z += __shfl_xor(z, 16);
            z += __shfl_xor(z, 32);
            float rv = vj / z;
            #pragma unroll
            for (int r = 0; r < 32; ++r) outp[r] += P[r] * rv;
        }
        #pragma unroll
        for (int r = 0; r < 32; ++r) {
            float v = outp[r];
            v += __shfl_xor(v, 1);
            v += __shfl_xor(v, 2);
            v += __shfl_xor(v, 4);
            v += __shfl_xor(v, 8);
            outp[r] = v;
        }
        __syncthreads();   // all vj reads done before VS overwrite
        if (c == 0) {
            #pragma unroll
            for (int r = 0; r < 32; ++r)
                VS[g*132 + rbase + r] = outp[r];
        }
    }
    __syncthreads();

    // ---- y_out = z + attnout (pure write, this block's 8 cols) ----
    {
        int row = tid >> 2, cp = (tid & 3) * 2;
        int c0i = h0 + cp, c1i = h0 + cp + 1;
        float z0 = bf2f(Ybuf[row*256 + (c0i & 128) + ((c0i & 127) ^ ((row & 7) << 3))]);
        float z1 = bf2f(Ybuf[row*256 + (c1i & 128) + ((c1i & 127) ^ ((row & 7) << 3))]);
        float2 ov;
        ov.x = z0 + VS[cp*132 + row];
        ov.y = z1 + VS[(cp+1)*132 + row];
        *(float2*)&y_out[(size_t)(b*TT + row)*EE + h0 + cp] = ov;
    }
}

// ---------------- xout = xin + relu(xin @ Wfc + bfc); K-split, B via global_load_lds
__global__ __launch_bounds__(256, 4) void fc_mfma(
        const float* __restrict__ xin, const ushort* __restrict__ WT,
        const float* __restrict__ bfc, float* __restrict__ xout) {
    __shared__ __align__(16) ushort As[64*128];
    __shared__ __align__(16) ushort Bs[64*128];
    int tid = threadIdx.x, lane = tid & 63, w = tid >> 6;
    int c0 = blockIdx.x * 64;
    int r0 = blockIdx.y * 64;

    f32x4 acc[4] = {};
    int rband = w*16 + (lane & 15);
    int kq = (lane >> 4) * 8;

    #pragma unroll
    for (int half = 0; half < 2; ++half) {
        if (half) __syncthreads();
        {
            int rsub = lane >> 5, cb = (lane & 31) * 4;
            for (int rr2 = w*2; rr2 < 64; rr2 += 8) {
                int rr = rr2 + rsub;
                float4 v = *(const float4*)&xin[(size_t)(r0 + rr)*EE + half*128 + cb];
                ushort4 hh; hh.x = f2bf(v.x); hh.y = f2bf(v.y); hh.z = f2bf(v.z); hh.w = f2bf(v.w);
                *(ushort4*)&As[rr*128 + (cb ^ ((rr & 7) << 3))] = hh;
            }
        }
        for (int rg = w*4; rg < 64; rg += 16) {
            int row = c0 + rg + (lane >> 4);
            const ushort* src = WT + (size_t)row*256 + half*128 + (lane & 15)*8;
            gload_lds16(src, &Bs[(size_t)rg*128]);
        }
        __syncthreads();
        for (int ks = 0; ks < 4; ++ks) {
            int kk = ks*32 + kq;
            bf16x8 a = *(const bf16x8*)&As[rband*128 + (kk ^ ((rband & 7) << 3))];
            #pragma unroll
            for (int n = 0; n < 4; ++n) {
                int c = n*16 + (lane & 15);
                bf16x8 b = *(const bf16x8*)&Bs[c*128 + (kk ^ ((c & 7) << 3))];
                acc[n] = __builtin_amdgcn_mfma_f32_16x16x32_bf16(a, b, acc[n], 0, 0, 0);
            }
        }
    }
    int grow0 = r0 + w*16 + ((lane >> 4) << 2);
    #pragma unroll
    for (int n = 0; n < 4; ++n) {
        int col = c0 + n*16 + (lane & 15);
        float bias = bfc[col];
        #pragma unroll
        for (int j = 0; j < 4; ++j) {
            size_t idx = (size_t)(grow0 + j)*EE + col;
            xout[idx] = xin[idx] + fmaxf(acc[n][j] + bias, 0.f);
        }
    }
}

// ---------------- lm: 128x128 tile, K-split, B via global_load_lds, coalesced f4 store
__global__ __launch_bounds__(512, 4) void lm_mfma_kernel(
        const float* __restrict__ x, const ushort* __restrict__ WlmT,
        const float* __restrict__ blm, float* __restrict__ out,
        float* __restrict__ pm, float* __restrict__ pz) {
    __shared__ __align__(16) char LDSb[128*132*4];   // 67.6KB union
    ushort* As = (ushort*)LDSb;
    ushort* Bs = (ushort*)LDSb + 128*128;
    float*  fst = (float*)LDSb;
    int tid = threadIdx.x;
    int lane = tid & 63, w = tid >> 6;
    int c0 = blockIdx.x * 128;
    int r0 = blockIdx.y * 128;

    int wr = (w >> 2) * 64, wc = (w & 3) * 32;
    f32x4 acc[4][2] = {};
    int kq = (lane >> 4) * 8;

    #pragma unroll
    for (int half = 0; half < 2; ++half) {
        if (half) __syncthreads();
        {
            int rsub = lane >> 5, cb = (lane & 31) * 4;
            for (int rr2 = w*2; rr2 < 128; rr2 += 16) {
                int rr = rr2 + rsub;
                float4 v = *(const float4*)&x[(size_t)(r0 + rr)*EE + half*128 + cb];
                ushort4 hh; hh.x = f2bf(v.x); hh.y = f2bf(v.y); hh.z = f2bf(v.z); hh.w = f2bf(v.w);
                *(ushort4*)&As[rr*128 + (cb ^ ((rr & 7) << 3))] = hh;
            }
        }
        for (int rg = w*4; rg < 128; rg += 32) {
            int row = c0 + rg + (lane >> 4);
            const ushort* src = WlmT + (size_t)row*256 + half*128 + (lane & 15)*8;
            gload_lds16(src, &Bs[(size_t)rg*128]);
        }
        __syncthreads();
        for (int ks = 0; ks < 4; ++ks) {
            int kk = ks*32 + kq;
            bf16x8 a[4], bfr[2];
            #pragma unroll
            for (int m = 0; m < 4; ++m) {
                int rband = wr + m*16 + (lane & 15);
                a[m] = *(const bf16x8*)&As[rband*128 + (kk ^ ((rband & 7) << 3))];
            }
            #pragma unroll
            for (int n = 0; n < 2; ++n) {
                int c = wc + n*16 + (lane & 15);
                bfr[n] = *(const bf16x8*)&Bs[c*128 + (kk ^ ((c & 7) << 3))];
            }
            #pragma unroll
            for (int m = 0; m < 4; ++m)
                #pragma unroll
                for (int n = 0; n < 2; ++n)
                    acc[m][n] = __builtin_amdgcn_mfma_f32_16x16x32_bf16(a[m], bfr[n], acc[m][n], 0, 0, 0);
        }
    }
    __syncthreads();

    float bias[2];
    #pragma unroll
    for (int n = 0; n < 2; ++n) bias[n] = blm[c0 + wc + n*16 + (lane & 15)];
    #pragma unroll
    for (int m = 0; m < 4; ++m) {
        int rw = wr + m*16 + (lane >> 4)*4;
        #pragma unroll
        for (int j = 0; j < 4; ++j) {
            int row = rw + j;
            float vals[2];
            float vmax = -INFINITY;
            #pragma unroll
            for (int n = 0; n < 2; ++n) {
                vals[n] = acc[m][n][j] + bias[n];
                fst[row*132 + wc + n*16 + (lane & 15)] = vals[n];
                vmax = fmaxf(vmax, vals[n]);
            }
            #pragma unroll
            for (int msk = 1; msk <= 8; msk <<= 1) vmax = fmaxf(vmax, __shfl_xor(vmax, msk));
            float z = 0.f;
            #pragma unroll
            for (int n = 0; n < 2; ++n) z += __expf(vals[n] - vmax);
            #pragma unroll
            for (int msk = 1; msk <= 8; msk <<= 1) z += __shfl_xor(z, msk);
            if ((lane & 15) == 0) {
                pm[(size_t)(r0 + row)*256 + blockIdx.x*4 + (w & 3)] = vmax;
                pz[(size_t)(r0 + row)*256 + blockIdx.x*4 + (w & 3)] = z;
            }
        }
    }
    __syncthreads();
    #pragma unroll
    for (int it = 0; it < 8; ++it) {
        int k = tid + it*512;
        int row = k >> 5, c4 = (k & 31)*4;
        float4 v = *(float4*)&fst[row*132 + c4];
        *(float4*)&out[(size_t)(r0 + row)*VV + c0 + c4] = v;
    }
}

// ---------------- per-row loss from 256 partials, atomicAdd mean into pre-zeroed cell
__global__ void loss_kernel(const float* __restrict__ pm, const float* __restrict__ pz,
                            const float* __restrict__ logits, const int* __restrict__ targets,
                            float* __restrict__ out_last) {
    int r = blockIdx.x;
    int t = threadIdx.x;             // 256
    __shared__ float sm[256], sz[256];
    float m = pm[(size_t)r*256 + t];
    float z = pz[(size_t)r*256 + t];
    sm[t] = m; __syncthreads();
    for (int s = 128; s > 0; s >>= 1) {
        if (t < s) sm[t] = fmaxf(sm[t], sm[t + s]);
        __syncthreads();
    }
    float M = sm[0];
    sz[t] = z * __expf(m - M); __syncthreads();
    for (int s = 128; s > 0; s >>= 1) {
        if (t < s) sz[t] += sz[t + s];
        __syncthreads();
    }
    if (t == 0) {
        float lse = M + logf(sz[0]);
        atomicAdd(out_last, (lse - logits[(size_t)r*VV + targets[r]]) * (1.0f / NROWS));
    }
}

extern "C" void kernel_launch(void* const* d_in, const int* in_sizes, int n_in,
                              void* d_out, int out_size, void* d_ws, size_t ws_size,
                              hipStream_t stream) {
    const int*   idxs    = (const int*)d_in[0];
    const int*   targets = (const int*)d_in[1];
    const float* emb     = (const float*)d_in[2];
    const float* pos     = (const float*)d_in[3];
    const float* Wq      = (const float*)d_in[4];
    const float* Wk      = (const float*)d_in[5];
    const float* Wv      = (const float*)d_in[6];
    const float* Wfc     = (const float*)d_in[7];
    const float* bfc     = (const float*)d_in[8];
    const float* Wlm     = (const float*)d_in[9];
    const float* blm     = (const float*)d_in[10];
    float* out = (float*)d_out;
    float* loss_cell = out + (size_t)NROWS * VV;

    float* ws = (float*)d_ws;
    float*  ya   = ws;                          // [1024,256]
    float*  yb   = ya + NROWS*EE;
    float*  pm   = yb + NROWS*EE;               // [1024,256]
    float*  pz   = pm + NROWS*256;
    ushort* WTs  = (ushort*)(pz + NROWS*256);   // 20 * 256*256 bf16 (SW128)
    ushort* WlmT = WTs + 20*EE*EE;              // 8192*256 bf16 (SW128)

    // launch 1: layer-0 qkv+attn (raw weights) + all prep jobs as extra blocks
    layer0_kernel<<<1089, 512, 0, stream>>>(idxs, emb, pos, Wq, Wk, Wv, Wfc, Wlm,
                                            ya, WTs, WlmT, loss_cell);

    // launches 2-5: fused (fc_{l-1} + qkv_l + attn_l), 2 blocks/CU
    for (int l = 1; l < LL; ++l) {
        const float* yi = (l & 1) ? ya : yb;
        float*       yo = (l & 1) ? yb : ya;
        layer_kernel<<<256, 512, 0, stream>>>(
            yi, yo,
            WTs + (size_t)((l-1)*4 + 3)*EE*EE, bfc + (size_t)(l-1)*EE,
            WTs + (size_t)l*4*EE*EE);
    }
    // fc4: ya (y4) -> yb (final x)
    fc_mfma<<<dim3(4, 16), 256, 0, stream>>>(ya, WTs + (size_t)(4*4 + 3)*EE*EE,
                                             bfc + 4*EE, yb);

    lm_mfma_kernel<<<dim3(VV/128, NROWS/128), 512, 0, stream>>>(yb, WlmT, blm, out, pm, pz);
    loss_kernel<<<NROWS, 256, 0, stream>>>(pm, pz, out, targets, loss_cell);
}

// Round 20
// 196.500 us; speedup vs baseline: 1.0505x; 1.0505x over previous
//
#include <hip/hip_runtime.h>

#define BB 8
#define TT 128
#define EE 256
#define VV 8192
#define LL 5
#define NROWS (BB*TT)   // 1024

typedef __attribute__((ext_vector_type(8))) short bf16x8;
typedef __attribute__((ext_vector_type(4))) float f32x4;

__device__ inline ushort f2bf(float f) {
    union { float f; unsigned u; } c; c.f = f;
    unsigned u = c.u;
    return (ushort)((u + 0x7FFF + ((u >> 16) & 1)) >> 16);  // RNE
}
__device__ inline float bf2f(ushort u) {
    union { unsigned u; float f; } c; c.u = ((unsigned)u) << 16;
    return c.f;
}

// async global->LDS copy, 16B per lane; lds base wave-uniform (HW adds lane*16)
__device__ __forceinline__ void gload_lds16(const void* g, void* l) {
    __builtin_amdgcn_global_load_lds((const __attribute__((address_space(1))) unsigned int*)g,
                                     (__attribute__((address_space(3))) unsigned int*)l,
                                     16, 0, 0);
}

// SW128 weight layout: W^T row r (output col), k in [0,256):
//   ushort index = r*256 + (k & 128) + ((k & 127) ^ ((r & 7) << 3))
// Full-width bf16 tile layout (Ybuf/Zbuf): row*256 + (k & 128) + ((k & 127) ^ ((row & 7) << 3))

// ---------------- layer0 kernel: blocks<256 = layer-0 qkv+attn (raw weights, inline emb);
// blocks>=256 = prep jobs (loss zero / WlmT / WTs transposes) riding along.
__global__ __launch_bounds__(512, 2) void layer0_kernel(
        const int* __restrict__ idxs, const float* __restrict__ emb, const float* __restrict__ pos,
        const float* __restrict__ Wq, const float* __restrict__ Wk,
        const float* __restrict__ Wv, const float* __restrict__ Wfc,
        const float* __restrict__ Wlm,
        float* __restrict__ y_out, ushort* __restrict__ WTs, ushort* __restrict__ WlmT,
        float* __restrict__ loss_cell) {
    __shared__ __align__(16) ushort Xs[128*128];   // 32KB (transpose blocks alias as ts)
    __shared__ __align__(16) ushort Bs[32*128];    // 8KB
    __shared__ __align__(16) float QS[8*132], KS[8*132], VS[8*132], MS[8*132]; // 16.9KB
    int tid = threadIdx.x, lane = tid & 63, w = tid >> 6;   // 8 waves
    int blk = blockIdx.x;

    if (blk >= 256) {
        // ---- prep jobs ----
        int id = blk - 256;
        if (id == 0) {
            if (tid == 0) *loss_cell = 0.f;
            return;
        }
        ushort (*ts)[72] = (ushort(*)[72])Xs;
        if (id < 513) {
            int idw = id - 1;
            int v0 = (idw & 127) * 64, k0 = (idw >> 7) * 64;
            for (int kk = w; kk < 64; kk += 8)
                ts[lane][kk] = f2bf(Wlm[(size_t)(k0 + kk)*VV + v0 + lane]);
            __syncthreads();
            for (int vv = w; vv < 64; vv += 8) {
                int r = v0 + vv, k = k0 + lane;
                WlmT[(size_t)r*256 + (k & 128) + ((k & 127) ^ ((r & 7) << 3))] = ts[vv][lane];
            }
            return;
        }
        {
            int idm = id - 513;
            int mat = idm >> 4, tile = idm & 15;
            int l = mat >> 2, type = mat & 3;
            const float* src = (type == 0 ? Wq : type == 1 ? Wk : type == 2 ? Wv : Wfc) + l*EE*EE;
            ushort* dst = WTs + mat*EE*EE;
            int i0 = (tile >> 2) * 64, o0 = (tile & 3) * 64;
            for (int ii = w; ii < 64; ii += 8)
                ts[lane][ii] = f2bf(src[(i0 + ii)*EE + o0 + lane]);
            __syncthreads();
            for (int oo = w; oo < 64; oo += 8) {
                int r = o0 + oo, k = i0 + lane;
                dst[(size_t)r*256 + (k & 128) + ((k & 127) ^ ((r & 7) << 3))] = ts[oo][lane];
            }
            return;
        }
    }

    // ---- layer-0 qkv+attn ----
    int b  = blk >> 5;
    int h0 = (blk & 31) * 8;

    f32x4 acc[2] = {};
    int rband = w*16 + (lane & 15);
    int kq = (lane >> 4) * 8;

    #pragma unroll
    for (int half = 0; half < 2; ++half) {
        if (half) __syncthreads();
        {
            int rsub = lane >> 5, cb = (lane & 31) * 4;
            for (int rr2 = w*2; rr2 < 128; rr2 += 16) {
                int rr = rr2 + rsub;
                int id = idxs[b*TT + rr];
                float4 v = *(const float4*)&emb[(size_t)id*EE + half*128 + cb];
                float4 p = *(const float4*)&pos[rr*EE + half*128 + cb];
                ushort4 hh;
                hh.x = f2bf(v.x + p.x); hh.y = f2bf(v.y + p.y);
                hh.z = f2bf(v.z + p.z); hh.w = f2bf(v.w + p.w);
                *(ushort4*)&Xs[rr*128 + (cb ^ ((rr & 7) << 3))] = hh;
            }
        }
        {
            int c = tid >> 4;            // 0..31
            int kb8 = (tid & 15) * 8;
            ushort tmp[8];
            if (c < 24) {
                int mat = c >> 3;
                int col = h0 + (c & 7);
                const float* Wm = mat == 0 ? Wq : (mat == 1 ? Wk : Wv);
                #pragma unroll
                for (int i = 0; i < 8; ++i)
                    tmp[i] = f2bf(Wm[(size_t)(half*128 + kb8 + i)*EE + col]);
            } else {
                #pragma unroll
                for (int i = 0; i < 8; ++i) tmp[i] = 0;
            }
            ushort* dst = &Bs[c*128 + (kb8 ^ ((c & 7) << 3))];
            *(ushort4*)dst       = *(ushort4*)&tmp[0];
            *(ushort4*)(dst + 4) = *(ushort4*)&tmp[4];
        }
        __syncthreads();
        for (int ks = 0; ks < 4; ++ks) {
            int kk = ks*32 + kq;
            bf16x8 a = *(const bf16x8*)&Xs[rband*128 + (kk ^ ((rband & 7) << 3))];
            #pragma unroll
            for (int ct = 0; ct < 2; ++ct) {
                int c = ct*16 + (lane & 15);
                bf16x8 bb = *(const bf16x8*)&Bs[c*128 + (kk ^ ((c & 7) << 3))];
                acc[ct] = __builtin_amdgcn_mfma_f32_16x16x32_bf16(a, bb, acc[ct], 0, 0, 0);
            }
        }
    }
    {
        int r_ = w*16 + ((lane >> 4) << 2);
        #pragma unroll
        for (int ct = 0; ct < 2; ++ct) {
            int col24 = ct*16 + (lane & 15);
            #pragma unroll
            for (int j = 0; j < 4; ++j) {
                float val = acc[ct][j];
                int row = r_ + j;
                if (col24 < 8)       QS[col24*132 + row] = val;
                else if (col24 < 16) KS[(col24-8)*132 + row] = val;
                else if (col24 < 24) VS[(col24-16)*132 + row] = val;
            }
        }
    }
    __syncthreads();

    int g = w, lg = lane;
    {
        int j0 = lg*2;
        float k0 = KS[g*132 + j0], k1 = KS[g*132 + j0 + 1];
        float q0j = QS[g*132 + j0], q1j = QS[g*132 + j0 + 1];
        float pmax = fmaxf(q0j, q1j), pmin = fminf(q0j, q1j);
        #pragma unroll
        for (int d = 1; d < 64; d <<= 1) {
            float om = __shfl_down(pmax, d);
            float on = __shfl_down(pmin, d);
            if (lg + d < 64) { pmax = fmaxf(pmax, om); pmin = fminf(pmin, on); }
        }
        float nx = __shfl_down(pmax, 1), nn = __shfl_down(pmin, 1);
        float sp1 = (lg == 63) ? q1j : fmaxf(q1j, nx);
        float sn1 = (lg == 63) ? q1j : fminf(q1j, nn);
        MS[g*132 + j0]     = (k0 >= 0.f) ? k0*pmax : k0*pmin;
        MS[g*132 + j0 + 1] = (k1 >= 0.f) ? k1*sp1  : k1*sn1;
    }
    __syncthreads();

    {
        float outp[32];
        #pragma unroll
        for (int r = 0; r < 32; ++r) outp[r] = 0.f;
        int c = lg & 15, rg = lg >> 4;
        int rbase = rg * 32;
        for (int jt = 0; jt < 8; ++jt) {
            int j = jt*16 + c;
            float kj = KS[g*132 + j];
            float mj = MS[g*132 + j];
            float vj = VS[g*132 + j];
            float P[32];
            float z = 0.f;
            #pragma unroll
            for (int r = 0; r < 32; ++r) {
                int i = rbase + r;
                float e = __expf(QS[g*132 + i] * kj - mj);
                e = (i >= j) ? e : 0.f;
                P[r] = e;
                z += e;
            }
            z += __shfl_xor(z, 16);
            z += __shfl_xor(z, 32);
            float rv = vj / z;
            #pragma unroll
            for (int r = 0; r < 32; ++r) outp[r] += P[r] * rv;
        }
        #pragma unroll
        for (int r = 0; r < 32; ++r) {
            float v = outp[r];
            v += __shfl_xor(v, 1);
            v += __shfl_xor(v, 2);
            v += __shfl_xor(v, 4);
            v += __shfl_xor(v, 8);
            outp[r] = v;
        }
        __syncthreads();   // all vj reads done before VS overwrite
        if (c == 0) {
            #pragma unroll
            for (int r = 0; r < 32; ++r)
                VS[g*132 + rbase + r] = outp[r];
        }
    }
    __syncthreads();

    {
        int row = tid >> 2, cp = (tid & 3) * 2;
        int id = idxs[b*TT + row];
        float2 ev = *(const float2*)&emb[(size_t)id*EE + h0 + cp];
        float2 pv = *(const float2*)&pos[row*EE + h0 + cp];
        float2 ov;
        ov.x = ev.x + pv.x + VS[cp*132 + row];
        ov.y = ev.y + pv.y + VS[(cp+1)*132 + row];
        *(float2*)&y_out[(size_t)(b*TT + row)*EE + h0 + cp] = ov;
    }
}

// ---------------- fused layer kernel (l=1..4): z = y + relu(y@Wfc_prev + b) in-LDS,
// then qkv (A=Zbuf) + attn + y_out = z + attnout. 256 blocks x 512 thr, 153KB LDS.
__global__ __launch_bounds__(512, 2) void layer_kernel(
        const float* __restrict__ y_in, float* __restrict__ y_out,
        const ushort* __restrict__ WTfc, const float* __restrict__ bfc_prev,
        const ushort* __restrict__ WTqkv) {
    __shared__ __align__(16) ushort Zbuf[128*256];   // 64KB z bf16, full-swizzled
    __shared__ __align__(16) ushort Ybuf[128*256];   // 64KB y bf16, full-swizzled
    __shared__ __align__(16) char U[25600];          // BsF 16KB  ∪  {Bsq 8KB | attn 16.9KB}
    ushort* BsF = (ushort*)U;                        // [64][128]
    ushort* Bsq = (ushort*)U;                        // [32][128]
    float* QS = (float*)(U + 8192);
    float* KS = QS + 8*132;
    float* VS = KS + 8*132;
    float* MS = VS + 8*132;
    int tid = threadIdx.x, lane = tid & 63, w = tid >> 6;   // 8 waves
    int b  = blockIdx.x >> 5;
    int h0 = (blockIdx.x & 31) * 8;
    int rband = w*16 + (lane & 15);
    int kq = (lane >> 4) * 8;

    // ---- phase A: stage y (full width) ----
    for (int rr = w; rr < 128; rr += 8) {
        float4 v = *(const float4*)&y_in[(size_t)(b*TT + rr)*EE + lane*4];
        ushort4 hh;
        hh.x = f2bf(v.x); hh.y = f2bf(v.y); hh.z = f2bf(v.z); hh.w = f2bf(v.w);
        int k0 = lane*4;
        *(ushort4*)&Ybuf[rr*256 + (k0 & 128) + ((k0 & 127) ^ ((rr & 7) << 3))] = hh;
    }
    __syncthreads();

    // fc MFMA: 2 halves x 4 col-groups, accz[cg][n]
    f32x4 accz[4][4] = {};
    #pragma unroll
    for (int half = 0; half < 2; ++half) {
        #pragma unroll
        for (int cg = 0; cg < 4; ++cg) {
            __syncthreads();        // BsF free (prev MFMA reads done)
            {
                int rg0 = w*8;
                const ushort* s0 = WTfc + (size_t)(cg*64 + rg0 + (lane >> 4))*256
                                 + half*128 + (lane & 15)*8;
                gload_lds16(s0, &BsF[(size_t)rg0*128]);
                const ushort* s1 = WTfc + (size_t)(cg*64 + rg0 + 4 + (lane >> 4))*256
                                 + half*128 + (lane & 15)*8;
                gload_lds16(s1, &BsF[(size_t)(rg0 + 4)*128]);
            }
            __syncthreads();
            for (int ks = 0; ks < 4; ++ks) {
                int kk = ks*32 + kq;
                bf16x8 a = *(const bf16x8*)&Ybuf[rband*256 + half*128 + (kk ^ ((rband & 7) << 3))];
                #pragma unroll
                for (int n = 0; n < 4; ++n) {
                    int c = n*16 + (lane & 15);
                    bf16x8 bb = *(const bf16x8*)&BsF[c*128 + (kk ^ ((c & 7) << 3))];
                    accz[cg][n] = __builtin_amdgcn_mfma_f32_16x16x32_bf16(a, bb, accz[cg][n], 0, 0, 0);
                }
            }
        }
    }
    // epilogue: z = y(bf16) + relu(acc + bias) -> Zbuf ; own-wave rows only
    {
        int grow0 = w*16 + ((lane >> 4) << 2);
        #pragma unroll
        for (int cg = 0; cg < 4; ++cg) {
            #pragma unroll
            for (int n = 0; n < 4; ++n) {
                int col = cg*64 + n*16 + (lane & 15);
                float bias = bfc_prev[col];
                int coff = (col & 128), csub = col & 127;
                #pragma unroll
                for (int j = 0; j < 4; ++j) {
                    int row = grow0 + j;
                    int sw = coff + (csub ^ ((row & 7) << 3));
                    float y = bf2f(Ybuf[row*256 + sw]);
                    float z = y + fmaxf(accz[cg][n][j] + bias, 0.f);
                    Zbuf[row*256 + sw] = f2bf(z);
                }
            }
        }
    }
    __syncthreads();   // Zbuf complete; BsF dead -> Bsq/attn region usable

    // ---- phase B: qkv, A = Zbuf ----
    f32x4 acc[2] = {};
    #pragma unroll
    for (int half = 0; half < 2; ++half) {
        if (half) __syncthreads();   // Bsq rewrite
        {
            int rowg = w*4 + (lane >> 4);
            int rowv = rowg < 24 ? rowg : 23;
            int mat = rowv >> 3, col = h0 + (rowv & 7);
            const ushort* src = WTqkv + (size_t)mat*EE*EE + (size_t)col*256
                              + half*128 + (lane & 15)*8;
            gload_lds16(src, &Bsq[(size_t)w*4*128]);
        }
        __syncthreads();
        for (int ks = 0; ks < 4; ++ks) {
            int kk = ks*32 + kq;
            bf16x8 a = *(const bf16x8*)&Zbuf[rband*256 + half*128 + (kk ^ ((rband & 7) << 3))];
            #pragma unroll
            for (int ct = 0; ct < 2; ++ct) {
                int c = ct*16 + (lane & 15);
                bf16x8 bb = *(const bf16x8*)&Bsq[c*128 + (kk ^ ((c & 7) << 3))];
                acc[ct] = __builtin_amdgcn_mfma_f32_16x16x32_bf16(a, bb, acc[ct], 0, 0, 0);
            }
        }
    }
    // scatter q|k|v (attn arrays don't alias Bsq)
    {
        int r_ = w*16 + ((lane >> 4) << 2);
        #pragma unroll
        for (int ct = 0; ct < 2; ++ct) {
            int col24 = ct*16 + (lane & 15);
            #pragma unroll
            for (int j = 0; j < 4; ++j) {
                float val = acc[ct][j];
                int row = r_ + j;
                if (col24 < 8)       QS[col24*132 + row] = val;
                else if (col24 < 16) KS[(col24-8)*132 + row] = val;
                else if (col24 < 24) VS[(col24-16)*132 + row] = val;
            }
        }
    }
    __syncthreads();

    // ---- phase C: attention (exp-once) ----
    int g = w, lg = lane;
    {
        int j0 = lg*2;
        float k0 = KS[g*132 + j0], k1 = KS[g*132 + j0 + 1];
        float q0j = QS[g*132 + j0], q1j = QS[g*132 + j0 + 1];
        float pmax = fmaxf(q0j, q1j), pmin = fminf(q0j, q1j);
        #pragma unroll
        for (int d = 1; d < 64; d <<= 1) {
            float om = __shfl_down(pmax, d);
            float on = __shfl_down(pmin, d);
            if (lg + d < 64) { pmax = fmaxf(pmax, om); pmin = fminf(pmin, on); }
        }
        float nx = __shfl_down(pmax, 1), nn = __shfl_down(pmin, 1);
        float sp1 = (lg == 63) ? q1j : fmaxf(q1j, nx);
        float sn1 = (lg == 63) ? q1j : fminf(q1j, nn);
        MS[g*132 + j0]     = (k0 >= 0.f) ? k0*pmax : k0*pmin;
        MS[g*132 + j0 + 1] = (k1 >= 0.f) ? k1*sp1  : k1*sn1;
    }
    __syncthreads();
    {
        float outp[32];
        #pragma unroll
        for (int r = 0; r < 32; ++r) outp[r] = 0.f;
        int c = lg & 15, rg = lg >> 4;
        int rbase = rg * 32;
        for (int jt = 0; jt < 8; ++jt) {
            int j = jt*16 + c;
            float kj = KS[g*132 + j];
            float mj = MS[g*132 + j];
            float vj = VS[g*132 + j];
            float P[32];
            float z = 0.f;
            #pragma unroll
            for (int r = 0; r < 32; ++r) {
                int i = rbase + r;
                float e = __expf(QS[g*132 + i] * kj - mj);
                e = (i >= j) ? e : 0.f;
                P[r] = e;
                z += e;
            }
            z += __shfl_xor(z, 16);
            z += __shfl_xor(z, 32);
            float rv = vj / z;
            #pragma unroll
            for (int r = 0; r < 32; ++r) outp[r] += P[r] * rv;
        }
        #pragma unroll
        for (int r = 0; r < 32; ++r) {
            float v = outp[r];
            v += __shfl_xor(v, 1);
            v += __shfl_xor(v, 2);
            v += __shfl_xor(v, 4);
            v += __shfl_xor(v, 8);
            outp[r] = v;
        }
        __syncthreads();
        if (c == 0) {
            #pragma unroll
            for (int r = 0; r < 32; ++r)
                VS[g*132 + rbase + r] = outp[r];
        }
    }
    __syncthreads();

    // ---- phase D: y_out = z + attnout (pure write, this block's 8 cols) ----
    {
        int row = tid >> 2, cp = (tid & 3) * 2;
        int c0i = h0 + cp, c1i = h0 + cp + 1;
        float z0 = bf2f(Zbuf[row*256 + (c0i & 128) + ((c0i & 127) ^ ((row & 7) << 3))]);
        float z1 = bf2f(Zbuf[row*256 + (c1i & 128) + ((c1i & 127) ^ ((row & 7) << 3))]);
        float2 ov;
        ov.x = z0 + VS[cp*132 + row];
        ov.y = z1 + VS[(cp+1)*132 + row];
        *(float2*)&y_out[(size_t)(b*TT + row)*EE + h0 + cp] = ov;
    }
}

// ---------------- xout = xin + relu(xin @ Wfc + bfc); K-split, B via global_load_lds
__global__ __launch_bounds__(256, 4) void fc_mfma(
        const float* __restrict__ xin, const ushort* __restrict__ WT,
        const float* __restrict__ bfc, float* __restrict__ xout) {
    __shared__ __align__(16) ushort As[64*128];
    __shared__ __align__(16) ushort Bs[64*128];
    int tid = threadIdx.x, lane = tid & 63, w = tid >> 6;
    int c0 = blockIdx.x * 64;
    int r0 = blockIdx.y * 64;

    f32x4 acc[4] = {};
    int rband = w*16 + (lane & 15);
    int kq = (lane >> 4) * 8;

    #pragma unroll
    for (int half = 0; half < 2; ++half) {
        if (half) __syncthreads();
        {
            int rsub = lane >> 5, cb = (lane & 31) * 4;
            for (int rr2 = w*2; rr2 < 64; rr2 += 8) {
                int rr = rr2 + rsub;
                float4 v = *(const float4*)&xin[(size_t)(r0 + rr)*EE + half*128 + cb];
                ushort4 hh; hh.x = f2bf(v.x); hh.y = f2bf(v.y); hh.z = f2bf(v.z); hh.w = f2bf(v.w);
                *(ushort4*)&As[rr*128 + (cb ^ ((rr & 7) << 3))] = hh;
            }
        }
        for (int rg = w*4; rg < 64; rg += 16) {
            int row = c0 + rg + (lane >> 4);
            const ushort* src = WT + (size_t)row*256 + half*128 + (lane & 15)*8;
            gload_lds16(src, &Bs[(size_t)rg*128]);
        }
        __syncthreads();
        for (int ks = 0; ks < 4; ++ks) {
            int kk = ks*32 + kq;
            bf16x8 a = *(const bf16x8*)&As[rband*128 + (kk ^ ((rband & 7) << 3))];
            #pragma unroll
            for (int n = 0; n < 4; ++n) {
                int c = n*16 + (lane & 15);
                bf16x8 b = *(const bf16x8*)&Bs[c*128 + (kk ^ ((c & 7) << 3))];
                acc[n] = __builtin_amdgcn_mfma_f32_16x16x32_bf16(a, b, acc[n], 0, 0, 0);
            }
        }
    }
    int grow0 = r0 + w*16 + ((lane >> 4) << 2);
    #pragma unroll
    for (int n = 0; n < 4; ++n) {
        int col = c0 + n*16 + (lane & 15);
        float bias = bfc[col];
        #pragma unroll
        for (int j = 0; j < 4; ++j) {
            size_t idx = (size_t)(grow0 + j)*EE + col;
            xout[idx] = xin[idx] + fmaxf(acc[n][j] + bias, 0.f);
        }
    }
}

// ---------------- lm: 128x128 tile, K-split, B via global_load_lds, coalesced f4 store
__global__ __launch_bounds__(512, 4) void lm_mfma_kernel(
        const float* __restrict__ x, const ushort* __restrict__ WlmT,
        const float* __restrict__ blm, float* __restrict__ out,
        float* __restrict__ pm, float* __restrict__ pz) {
    __shared__ __align__(16) char LDSb[128*132*4];   // 67.6KB union
    ushort* As = (ushort*)LDSb;
    ushort* Bs = (ushort*)LDSb + 128*128;
    float*  fst = (float*)LDSb;
    int tid = threadIdx.x;
    int lane = tid & 63, w = tid >> 6;
    int c0 = blockIdx.x * 128;
    int r0 = blockIdx.y * 128;

    int wr = (w >> 2) * 64, wc = (w & 3) * 32;
    f32x4 acc[4][2] = {};
    int kq = (lane >> 4) * 8;

    #pragma unroll
    for (int half = 0; half < 2; ++half) {
        if (half) __syncthreads();
        {
            int rsub = lane >> 5, cb = (lane & 31) * 4;
            for (int rr2 = w*2; rr2 < 128; rr2 += 16) {
                int rr = rr2 + rsub;
                float4 v = *(const float4*)&x[(size_t)(r0 + rr)*EE + half*128 + cb];
                ushort4 hh; hh.x = f2bf(v.x); hh.y = f2bf(v.y); hh.z = f2bf(v.z); hh.w = f2bf(v.w);
                *(ushort4*)&As[rr*128 + (cb ^ ((rr & 7) << 3))] = hh;
            }
        }
        for (int rg = w*4; rg < 128; rg += 32) {
            int row = c0 + rg + (lane >> 4);
            const ushort* src = WlmT + (size_t)row*256 + half*128 + (lane & 15)*8;
            gload_lds16(src, &Bs[(size_t)rg*128]);
        }
        __syncthreads();
        for (int ks = 0; ks < 4; ++ks) {
            int kk = ks*32 + kq;
            bf16x8 a[4], bfr[2];
            #pragma unroll
            for (int m = 0; m < 4; ++m) {
                int rband = wr + m*16 + (lane & 15);
                a[m] = *(const bf16x8*)&As[rband*128 + (kk ^ ((rband & 7) << 3))];
            }
            #pragma unroll
            for (int n = 0; n < 2; ++n) {
                int c = wc + n*16 + (lane & 15);
                bfr[n] = *(const bf16x8*)&Bs[c*128 + (kk ^ ((c & 7) << 3))];
            }
            #pragma unroll
            for (int m = 0; m < 4; ++m)
                #pragma unroll
                for (int n = 0; n < 2; ++n)
                    acc[m][n] = __builtin_amdgcn_mfma_f32_16x16x32_bf16(a[m], bfr[n], acc[m][n], 0, 0, 0);
        }
    }
    __syncthreads();

    float bias[2];
    #pragma unroll
    for (int n = 0; n < 2; ++n) bias[n] = blm[c0 + wc + n*16 + (lane & 15)];
    #pragma unroll
    for (int m = 0; m < 4; ++m) {
        int rw = wr + m*16 + (lane >> 4)*4;
        #pragma unroll
        for (int j = 0; j < 4; ++j) {
            int row = rw + j;
            float vals[2];
            float vmax = -INFINITY;
            #pragma unroll
            for (int n = 0; n < 2; ++n) {
                vals[n] = acc[m][n][j] + bias[n];
                fst[row*132 + wc + n*16 + (lane & 15)] = vals[n];
                vmax = fmaxf(vmax, vals[n]);
            }
            #pragma unroll
            for (int msk = 1; msk <= 8; msk <<= 1) vmax = fmaxf(vmax, __shfl_xor(vmax, msk));
            float z = 0.f;
            #pragma unroll
            for (int n = 0; n < 2; ++n) z += __expf(vals[n] - vmax);
            #pragma unroll
            for (int msk = 1; msk <= 8; msk <<= 1) z += __shfl_xor(z, msk);
            if ((lane & 15) == 0) {
                pm[(size_t)(r0 + row)*256 + blockIdx.x*4 + (w & 3)] = vmax;
                pz[(size_t)(r0 + row)*256 + blockIdx.x*4 + (w & 3)] = z;
            }
        }
    }
    __syncthreads();
    #pragma unroll
    for (int it = 0; it < 8; ++it) {
        int k = tid + it*512;
        int row = k >> 5, c4 = (k & 31)*4;
        float4 v = *(float4*)&fst[row*132 + c4];
        *(float4*)&out[(size_t)(r0 + row)*VV + c0 + c4] = v;
    }
}

// ---------------- per-row loss from 256 partials, atomicAdd mean into pre-zeroed cell
__global__ void loss_kernel(const float* __restrict__ pm, const float* __restrict__ pz,
                            const float* __restrict__ logits, const int* __restrict__ targets,
                            float* __restrict__ out_last) {
    int r = blockIdx.x;
    int t = threadIdx.x;             // 256
    __shared__ float sm[256], sz[256];
    float m = pm[(size_t)r*256 + t];
    float z = pz[(size_t)r*256 + t];
    sm[t] = m; __syncthreads();
    for (int s = 128; s > 0; s >>= 1) {
        if (t < s) sm[t] = fmaxf(sm[t], sm[t + s]);
        __syncthreads();
    }
    float M = sm[0];
    sz[t] = z * __expf(m - M); __syncthreads();
    for (int s = 128; s > 0; s >>= 1) {
        if (t < s) sz[t] += sz[t + s];
        __syncthreads();
    }
    if (t == 0) {
        float lse = M + logf(sz[0]);
        atomicAdd(out_last, (lse - logits[(size_t)r*VV + targets[r]]) * (1.0f / NROWS));
    }
}

extern "C" void kernel_launch(void* const* d_in, const int* in_sizes, int n_in,
                              void* d_out, int out_size, void* d_ws, size_t ws_size,
                              hipStream_t stream) {
    const int*   idxs    = (const int*)d_in[0];
    const int*   targets = (const int*)d_in[1];
    const float* emb     = (const float*)d_in[2];
    const float* pos     = (const float*)d_in[3];
    const float* Wq      = (const float*)d_in[4];
    const float* Wk      = (const float*)d_in[5];
    const float* Wv      = (const float*)d_in[6];
    const float* Wfc     = (const float*)d_in[7];
    const float* bfc     = (const float*)d_in[8];
    const float* Wlm     = (const float*)d_in[9];
    const float* blm     = (const float*)d_in[10];
    float* out = (float*)d_out;
    float* loss_cell = out + (size_t)NROWS * VV;

    float* ws = (float*)d_ws;
    float*  ya   = ws;                          // [1024,256]
    float*  yb   = ya + NROWS*EE;
    float*  pm   = yb + NROWS*EE;               // [1024,256]
    float*  pz   = pm + NROWS*256;
    ushort* WTs  = (ushort*)(pz + NROWS*256);   // 20 * 256*256 bf16 (SW128)
    ushort* WlmT = WTs + 20*EE*EE;              // 8192*256 bf16 (SW128)

    // launch 1: layer-0 qkv+attn (raw weights) + all prep jobs as extra blocks
    layer0_kernel<<<1089, 512, 0, stream>>>(idxs, emb, pos, Wq, Wk, Wv, Wfc, Wlm,
                                            ya, WTs, WlmT, loss_cell);

    // launches 2-5: fused (fc_{l-1} + qkv_l + attn_l)
    // L1: ya->yb, L2: yb->ya, L3: ya->yb, L4: yb->ya
    for (int l = 1; l < LL; ++l) {
        const float* yi = (l & 1) ? ya : yb;
        float*       yo = (l & 1) ? yb : ya;
        layer_kernel<<<256, 512, 0, stream>>>(
            yi, yo,
            WTs + (size_t)((l-1)*4 + 3)*EE*EE, bfc + (size_t)(l-1)*EE,
            WTs + (size_t)l*4*EE*EE);
    }
    // fc4: ya (y4) -> yb (final x)
    fc_mfma<<<dim3(4, 16), 256, 0, stream>>>(ya, WTs + (size_t)(4*4 + 3)*EE*EE,
                                             bfc + 4*EE, yb);

    lm_mfma_kernel<<<dim3(VV/128, NROWS/128), 512, 0, stream>>>(yb, WlmT, blm, out, pm, pz);
    loss_kernel<<<NROWS, 256, 0, stream>>>(pm, pz, out, targets, loss_cell);
}